// Round 10
// baseline (252.697 us; speedup 1.0000x reference)
//
#include <hip/hip_runtime.h>

// ===== R10: edges-last step ordering (barrier-residue overlap), REPEAT=3 =====
// Ledger: write rate pinned 4.7-4.8 TB/s across sync style, occupancy, store
// balance, inter-block phase; 128B segments -> 3.78 (pattern floor), but
// 256B vs 512B identical. Untested variable: barrier POSITION. All previous
// variants begin each step with ds_write+lgkmcnt+barrier+ds_read before any
// store issues (~0.6us/step of store silence = the additive gap). This
// round: publish boundaries first, compute+store 7 INTERIOR rows (need no
// neighbor data), then barrier (already satisfied), read neighbors, finish
// 2 edge rows. Rendezvous + LDS latency hide under interior stencil+stores.
// Everything else = R5: K=9, 4 blocks/CU, double-buffered board, nt stores.

namespace {

typedef float f4 __attribute__((ext_vector_type(4)));

constexpr int   REPEAT = 3;     // diagnostic replication (drop when tuned)
constexpr int   B      = 8;
constexpr int   N      = 2048;
constexpr int   D4     = 32;    // 128 floats = 32 f4 per row (global)
constexpr int   SPLITD = 2;
constexpr int   D4L    = D4 / SPLITD;   // 16 f4 lanes per block
constexpr int   STEPS  = 50;
constexpr float ALPHA  = 0.1f;
constexpr int   T      = 32;    // owned rows per block
constexpr int   QG     = 16;    // q-groups (256 thr / 16 lanes)
constexpr int   K      = 9;     // rows per thread
constexpr int   R      = QG * K;        // 144 staged rows
constexpr int   HALO_L = (R - T) / 2;   // 56 >= 50
constexpr int   CHUNKS = N / T;         // 64

__device__ __forceinline__ f4 stencil(const f4 p, const f4 c, const f4 n) {
    return c + ALPHA * (p + n - 2.0f * c);
}

__global__ __launch_bounds__(QG * D4L, 4) void diffusion_halo(
        const f4* __restrict__ in4, f4* __restrict__ out4) {
    const int tid = threadIdx.x;
    const int d4l = tid & (D4L - 1);  // f4 lane within this d-half
    const int q   = tid >> 4;         // row-group 0..15

    const int bid = blockIdx.x;
    const int dh  = bid & (SPLITD - 1);
    const int c   = (bid >> 1) & (CHUNKS - 1);
    const int b   = bid >> 7;
    const int n0  = c * T;
    const int d4g = dh * D4L + d4l;

    // Double-buffered boundary board: one barrier per step.
    __shared__ f4 lo[2][QG][D4L];
    __shared__ f4 hi[2][QG][D4L];

    const int rbase = q * K;

    for (int rep = 0; rep < REPEAT; ++rep) {
        f4 s[K];
        // Load K rows with wraparound: ng = (n0 + r - HALO_L) mod N.
#pragma unroll
        for (int i = 0; i < K; ++i) {
            const int ng = (n0 + rbase + i + (N - HALO_L)) & (N - 1);
            s[i] = in4[(b * N + ng) * D4 + d4g];
        }

        // out[0] = initial state (owned rows only)
#pragma unroll
        for (int i = 0; i < K; ++i) {
            const int r = rbase + i;
            if (r >= HALO_L && r < HALO_L + T) {
                __builtin_nontemporal_store(
                    s[i], &out4[(b * N + (n0 + r - HALO_L)) * D4 + d4g]);
            }
        }

        for (int k = 1; k <= STEPS; ++k) {
            const int buf = k & 1;
            // (1) Publish OLD boundary rows immediately.
            lo[buf][q][d4l] = s[0];
            hi[buf][q][d4l] = s[K - 1];

            // Save old values consumed by the deferred edge updates.
            const f4 old0  = s[0];
            const f4 old1  = s[1];
            const f4 oldK2 = s[K - 2];
            const f4 oldK1 = s[K - 1];

            // (2) Interior rows i=1..K-2: no neighbor data needed.
            //     Stores issue while other waves are still converging.
            const int outbase = (k * B + b) * N;
            f4 prev = old0;
#pragma unroll
            for (int i = 1; i <= K - 2; ++i) {
                const f4 cur = s[i];
                const f4 nxt = (i < K - 2) ? s[i + 1] : oldK1;
                s[i] = stencil(prev, cur, nxt);
                prev = cur;
                const int r = rbase + i;
                if (r >= HALO_L && r < HALO_L + T) {
                    __builtin_nontemporal_store(
                        s[i],
                        &out4[(outbase + (n0 + r - HALO_L)) * D4 + d4g]);
                }
            }

            // (3) Barrier — ds_writes issued ~0.5us ago; wait is short.
            asm volatile("s_waitcnt lgkmcnt(0)" ::: "memory");
            __builtin_amdgcn_s_barrier();
            const f4 bl = (q > 0)      ? hi[buf][q - 1][d4l] : (f4)(0.f);
            const f4 bh = (q < QG - 1) ? lo[buf][q + 1][d4l] : (f4)(0.f);
            // No second barrier: next iter writes buf^1; buf reuse two steps
            // later is fenced by the intervening lgkmcnt(0)+barrier.

            // (4) Edge rows (old-value inputs saved above).
            s[0] = stencil(bl, old0, old1);
            {
                const int r = rbase;
                if (r >= HALO_L && r < HALO_L + T) {
                    __builtin_nontemporal_store(
                        s[0],
                        &out4[(outbase + (n0 + r - HALO_L)) * D4 + d4g]);
                }
            }
            s[K - 1] = stencil(oldK2, oldK1, bh);
            {
                const int r = rbase + K - 1;
                if (r >= HALO_L && r < HALO_L + T) {
                    __builtin_nontemporal_store(
                        s[K - 1],
                        &out4[(outbase + (n0 + r - HALO_L)) * D4 + d4g]);
                }
            }
        }
    }
}

}  // namespace

extern "C" void kernel_launch(void* const* d_in, const int* in_sizes, int n_in,
                              void* d_out, int out_size, void* d_ws, size_t ws_size,
                              hipStream_t stream) {
    const f4* in4  = reinterpret_cast<const f4*>(d_in[0]);
    f4*       out4 = reinterpret_cast<f4*>(d_out);

    dim3 grid(B * CHUNKS * SPLITD);  // 1024 blocks -> 4 per CU
    dim3 block(QG * D4L);            // 256 threads
    diffusion_halo<<<grid, block, 0, stream>>>(in4, out4);
}